// Round 1
// baseline (18320.470 us; speedup 1.0000x reference)
//
#include <hip/hip_runtime.h>
#include <hip/hip_bf16.h>
#include <math.h>

#define V_   32000
#define D_   512
#define L_   6
#define H_   8
#define DH_  64
#define DFF_ 2048
#define B_   8
#define T_   1024
#define BT_  (B_*T_)

// ---------------- embedding: x = wte[idx] + wpe[t] ----------------
__global__ __launch_bounds__(128) void embed_kernel(
        const int* __restrict__ idx, const float* __restrict__ wte,
        const float* __restrict__ wpe, float* __restrict__ x) {
    int bt = blockIdx.x;
    int t  = bt & (T_ - 1);
    int tok = idx[bt];
    const float4* wr = (const float4*)(wte + (size_t)tok * D_);
    const float4* pr = (const float4*)(wpe + (size_t)t * D_);
    float4* xr = (float4*)(x + (size_t)bt * D_);
    int i = threadIdx.x;                     // 0..127, 4 floats each
    float4 a = wr[i], b = pr[i];
    xr[i] = make_float4(a.x + b.x, a.y + b.y, a.z + b.z, a.w + b.w);
}

// ---------------- layernorm: one block per token ----------------
__global__ __launch_bounds__(128) void ln_kernel(
        const float* __restrict__ x, const float* __restrict__ g,
        const float* __restrict__ b, float* __restrict__ out) {
    int bt = blockIdx.x;
    int i  = threadIdx.x;                    // 128 threads x float4
    float4 v = ((const float4*)(x + (size_t)bt * D_))[i];
    float s  = v.x + v.y + v.z + v.w;
    float sq = v.x*v.x + v.y*v.y + v.z*v.z + v.w*v.w;
    #pragma unroll
    for (int o = 32; o > 0; o >>= 1) {
        s  += __shfl_down(s,  o);
        sq += __shfl_down(sq, o);
    }
    __shared__ float ss[2], ssq[2];
    if ((i & 63) == 0) { ss[i >> 6] = s; ssq[i >> 6] = sq; }
    __syncthreads();
    float mean = (ss[0] + ss[1]) * (1.0f / D_);
    float var  = (ssq[0] + ssq[1]) * (1.0f / D_) - mean * mean;
    float rstd = rsqrtf(var + 1e-5f);
    float4 gg = ((const float4*)g)[i];
    float4 bb = ((const float4*)b)[i];
    float4 o4;
    o4.x = (v.x - mean) * rstd * gg.x + bb.x;
    o4.y = (v.y - mean) * rstd * gg.y + bb.y;
    o4.z = (v.z - mean) * rstd * gg.z + bb.z;
    o4.w = (v.w - mean) * rstd * gg.w + bb.w;
    ((float4*)(out + (size_t)bt * D_))[i] = o4;
}

__device__ __forceinline__ float gelu_exact(float v) {
    return 0.5f * v * (1.0f + erff(v * 0.70710678118654752f));
}

// ---------------- fp32 tiled GEMM with fused epilogue ----------------
// C[M,N] = act(A[M,K] @ B + bias) + res ; B is [K,N] (or [N,K] if TRANSB)
// 64x64 tile, BK=16, 256 threads, 4x4 acc per thread.
template<bool TRANSB>
__global__ __launch_bounds__(256) void gemm_kernel(
        const float* __restrict__ A, const float* __restrict__ Bm,
        const float* __restrict__ bias, const float* __restrict__ res,
        float* __restrict__ C, int M, int N, int K, int act)
{
    __shared__ __align__(16) float As[16][68];
    __shared__ __align__(16) float Bs[16][68];
    int t    = threadIdx.x;
    int row0 = blockIdx.y * 64;
    int col0 = blockIdx.x * 64;
    int tm   = (t & 15) * 4;       // row quad in tile
    int tn   = (t >> 4) * 4;       // col quad in tile
    float acc[4][4] = {};

    for (int k0 = 0; k0 < K; k0 += 16) {
        {   // A tile: 64 rows x 16 k, each thread one float4 along k
            int m = t >> 2, kq = (t & 3) * 4;
            float4 a4 = *(const float4*)&A[(size_t)(row0 + m) * K + k0 + kq];
            As[kq+0][m] = a4.x; As[kq+1][m] = a4.y;
            As[kq+2][m] = a4.z; As[kq+3][m] = a4.w;
        }
        if (!TRANSB) {  // B tile 16k x 64n, coalesced along n
            int kk = t >> 4, nq = (t & 15) * 4;
            float4 b4 = *(const float4*)&Bm[(size_t)(k0 + kk) * N + col0 + nq];
            *(float4*)&Bs[kk][nq] = b4;
        } else {        // B is [N,K]: read along k, scatter
            int n = t >> 2, kq = (t & 3) * 4;
            float4 b4 = *(const float4*)&Bm[(size_t)(col0 + n) * K + k0 + kq];
            Bs[kq+0][n] = b4.x; Bs[kq+1][n] = b4.y;
            Bs[kq+2][n] = b4.z; Bs[kq+3][n] = b4.w;
        }
        __syncthreads();
        #pragma unroll
        for (int k = 0; k < 16; ++k) {
            float4 a = *(const float4*)&As[k][tm];
            float4 b = *(const float4*)&Bs[k][tn];
            float av[4] = {a.x, a.y, a.z, a.w};
            float bv[4] = {b.x, b.y, b.z, b.w};
            #pragma unroll
            for (int i2 = 0; i2 < 4; ++i2)
                #pragma unroll
                for (int j2 = 0; j2 < 4; ++j2)
                    acc[i2][j2] = fmaf(av[i2], bv[j2], acc[i2][j2]);
        }
        __syncthreads();
    }

    float4 bv4 = make_float4(0.f, 0.f, 0.f, 0.f);
    if (bias) bv4 = *(const float4*)&bias[col0 + tn];
    #pragma unroll
    for (int i2 = 0; i2 < 4; ++i2) {
        float4 v;
        v.x = acc[i2][0] + bv4.x;
        v.y = acc[i2][1] + bv4.y;
        v.z = acc[i2][2] + bv4.z;
        v.w = acc[i2][3] + bv4.w;
        if (act == 1) {
            v.x = gelu_exact(v.x); v.y = gelu_exact(v.y);
            v.z = gelu_exact(v.z); v.w = gelu_exact(v.w);
        }
        size_t off = (size_t)(row0 + tm + i2) * N + col0 + tn;
        if (res) {
            float4 r = *(const float4*)&res[off];
            v.x += r.x; v.y += r.y; v.z += r.z; v.w += r.w;
        }
        *(float4*)&C[off] = v;
    }
}

// ---------------- causal attention: one block per (b,h,q) row ----------------
// qkv layout: [BT][3*D], q at +h*DH, k at +D+h*DH, v at +2D+h*DH
__global__ __launch_bounds__(256) void attn_kernel(
        const float* __restrict__ qkv, float* __restrict__ y) {
    int q  = blockIdx.x & (T_ - 1);
    int bh = blockIdx.x >> 10;
    int h  = bh & (H_ - 1);
    int b  = bh >> 3;
    int nk = q + 1;
    int t  = threadIdx.x;

    __shared__ __align__(16) float qs[DH_];
    __shared__ __align__(16) float sbuf[T_];
    __shared__ float red[8];
    __shared__ float ypart[4][DH_];

    const float* qrow = qkv + (size_t)(b * T_ + q) * (3 * D_) + h * DH_;
    if (t < DH_) qs[t] = qrow[t] * 0.125f;   // 1/sqrt(64)
    __syncthreads();

    // scores
    float lmax = -INFINITY;
    for (int j = t; j < nk; j += 256) {
        const float4* krow = (const float4*)(qkv + (size_t)(b * T_ + j) * (3 * D_) + D_ + h * DH_);
        float s = 0.f;
        #pragma unroll
        for (int d4 = 0; d4 < 16; ++d4) {
            float4 kv = krow[d4];
            float4 qv = *(const float4*)&qs[d4 * 4];
            s += qv.x * kv.x + qv.y * kv.y + qv.z * kv.z + qv.w * kv.w;
        }
        sbuf[j] = s;
        lmax = fmaxf(lmax, s);
    }
    #pragma unroll
    for (int o = 32; o > 0; o >>= 1) lmax = fmaxf(lmax, __shfl_down(lmax, o));
    if ((t & 63) == 0) red[t >> 6] = lmax;
    __syncthreads();
    float bmax = fmaxf(fmaxf(red[0], red[1]), fmaxf(red[2], red[3]));

    float lsum = 0.f;
    for (int j = t; j < nk; j += 256) {
        float p = __expf(sbuf[j] - bmax);
        sbuf[j] = p;
        lsum += p;
    }
    #pragma unroll
    for (int o = 32; o > 0; o >>= 1) lsum += __shfl_down(lsum, o);
    if ((t & 63) == 0) red[4 + (t >> 6)] = lsum;
    __syncthreads();
    float inv = 1.0f / (red[4] + red[5] + red[6] + red[7]);

    // y[d] = sum_j p_j * v[j][d]
    int d = t & 63;
    int g = t >> 6;
    float acc = 0.f;
    for (int j = g; j < nk; j += 4)
        acc += sbuf[j] * qkv[(size_t)(b * T_ + j) * (3 * D_) + 2 * D_ + h * DH_ + d];
    ypart[g][d] = acc;
    __syncthreads();
    if (t < DH_) {
        float r = (ypart[0][t] + ypart[1][t] + ypart[2][t] + ypart[3][t]) * inv;
        y[(size_t)(b * T_ + q) * D_ + h * DH_ + t] = r;
    }
}

// ---------------- launcher ----------------
extern "C" void kernel_launch(void* const* d_in, const int* in_sizes, int n_in,
                              void* d_out, int out_size, void* d_ws, size_t ws_size,
                              hipStream_t stream) {
    const int*   idx   = (const int*)  d_in[0];
    const float* wte   = (const float*)d_in[1];
    const float* wpe   = (const float*)d_in[2];
    const float* ln1_g = (const float*)d_in[3];
    const float* ln1_b = (const float*)d_in[4];
    const float* w_qkv = (const float*)d_in[5];
    const float* b_qkv = (const float*)d_in[6];
    const float* w_ao  = (const float*)d_in[7];
    const float* b_ao  = (const float*)d_in[8];
    const float* ln2_g = (const float*)d_in[9];
    const float* ln2_b = (const float*)d_in[10];
    const float* w_fc  = (const float*)d_in[11];
    const float* b_fc  = (const float*)d_in[12];
    const float* w_pr  = (const float*)d_in[13];
    const float* b_pr  = (const float*)d_in[14];
    const float* lnf_g = (const float*)d_in[15];
    const float* lnf_b = (const float*)d_in[16];
    float* outf = (float*)d_out;

    // scratch layout: big transient buffers live in d_out (only fully written
    // by the final head GEMM, which reads only hbuf); x,h persist in d_ws.
    size_t nx = (size_t)BT_ * D_;
    float* qkvbuf = outf;                           // BT*3D
    float* fcbuf  = outf + (size_t)BT_ * 3 * D_;    // BT*DFF
    float* xbuf;
    float* hbuf;
    if (ws_size >= 2 * nx * sizeof(float)) {
        xbuf = (float*)d_ws;
        hbuf = (float*)d_ws + nx;
    } else {                                        // small-ws fallback
        hbuf = (float*)d_ws;
        xbuf = fcbuf + (size_t)BT_ * DFF_;
    }

    embed_kernel<<<BT_, 128, 0, stream>>>(idx, wte, wpe, xbuf);

    for (int l = 0; l < L_; ++l) {
        ln_kernel<<<BT_, 128, 0, stream>>>(xbuf, ln1_g + l * D_, ln1_b + l * D_, hbuf);
        gemm_kernel<false><<<dim3(3 * D_ / 64, BT_ / 64), 256, 0, stream>>>(
            hbuf, w_qkv + (size_t)l * D_ * 3 * D_, b_qkv + l * 3 * D_,
            nullptr, qkvbuf, BT_, 3 * D_, D_, 0);
        attn_kernel<<<B_ * H_ * T_, 256, 0, stream>>>(qkvbuf, hbuf);
        gemm_kernel<false><<<dim3(D_ / 64, BT_ / 64), 256, 0, stream>>>(
            hbuf, w_ao + (size_t)l * D_ * D_, b_ao + l * D_,
            xbuf, xbuf, BT_, D_, D_, 0);
        ln_kernel<<<BT_, 128, 0, stream>>>(xbuf, ln2_g + l * D_, ln2_b + l * D_, hbuf);
        gemm_kernel<false><<<dim3(DFF_ / 64, BT_ / 64), 256, 0, stream>>>(
            hbuf, w_fc + (size_t)l * D_ * DFF_, b_fc + l * DFF_,
            nullptr, fcbuf, BT_, DFF_, D_, 1);
        gemm_kernel<false><<<dim3(D_ / 64, BT_ / 64), 256, 0, stream>>>(
            fcbuf, w_pr + (size_t)l * DFF_ * D_, b_pr + l * D_,
            xbuf, xbuf, BT_, D_, DFF_, 0);
    }

    ln_kernel<<<BT_, 128, 0, stream>>>(xbuf, lnf_g, lnf_b, hbuf);
    gemm_kernel<true><<<dim3(V_ / 64, BT_ / 64), 256, 0, stream>>>(
        hbuf, wte, nullptr, nullptr, outf, BT_, V_, D_, 0);
}

// Round 2
// 3575.517 us; speedup vs baseline: 5.1239x; 5.1239x over previous
//
#include <hip/hip_runtime.h>
#include <hip/hip_bf16.h>
#include <math.h>

#define V_   32000
#define D_   512
#define L_   6
#define H_   8
#define DH_  64
#define DFF_ 2048
#define B_   8
#define T_   1024
#define BT_  (B_*T_)

typedef __attribute__((ext_vector_type(4))) float f32x4;
typedef __attribute__((ext_vector_type(8))) short short8;
using bf16_t = __hip_bfloat16;

__device__ __forceinline__ float b2f(unsigned short u) {
    union { unsigned int i; float f; } v; v.i = ((unsigned int)u) << 16; return v.f;
}
__device__ __forceinline__ unsigned short f2b(float f) {
    bf16_t h = __float2bfloat16(f);
    return *reinterpret_cast<unsigned short*>(&h);
}
__device__ __forceinline__ void gl16(const void* g, void* l) {
    __builtin_amdgcn_global_load_lds((const __attribute__((address_space(1))) void*)g,
                                     (__attribute__((address_space(3))) void*)l, 16, 0, 0);
}
__device__ __forceinline__ float gelu_exact(float v) {
    return 0.5f * v * (1.0f + erff(v * 0.70710678118654752f));
}

// ---------------- embedding: x = wte[idx] + wpe[t] (fp32 residual) --------
__global__ __launch_bounds__(128) void embed_kernel(
        const int* __restrict__ idx, const float* __restrict__ wte,
        const float* __restrict__ wpe, float* __restrict__ x) {
    int bt = blockIdx.x;
    int t  = bt & (T_ - 1);
    int tok = idx[bt];
    const float4* wr = (const float4*)(wte + (size_t)tok * D_);
    const float4* pr = (const float4*)(wpe + (size_t)t * D_);
    float4* xr = (float4*)(x + (size_t)bt * D_);
    int i = threadIdx.x;
    float4 a = wr[i], b = pr[i];
    xr[i] = make_float4(a.x + b.x, a.y + b.y, a.z + b.z, a.w + b.w);
}

// ---------------- layernorm fp32 in -> bf16 out ----------------
__global__ __launch_bounds__(128) void ln_kernel(
        const float* __restrict__ x, const float* __restrict__ g,
        const float* __restrict__ b, bf16_t* __restrict__ out) {
    int bt = blockIdx.x;
    int i  = threadIdx.x;
    float4 v = ((const float4*)(x + (size_t)bt * D_))[i];
    float s  = v.x + v.y + v.z + v.w;
    float sq = v.x*v.x + v.y*v.y + v.z*v.z + v.w*v.w;
    #pragma unroll
    for (int o = 32; o > 0; o >>= 1) {
        s  += __shfl_down(s,  o);
        sq += __shfl_down(sq, o);
    }
    __shared__ float ss[2], ssq[2];
    if ((i & 63) == 0) { ss[i >> 6] = s; ssq[i >> 6] = sq; }
    __syncthreads();
    float mean = (ss[0] + ss[1]) * (1.0f / D_);
    float var  = (ssq[0] + ssq[1]) * (1.0f / D_) - mean * mean;
    float rstd = rsqrtf(var + 1e-5f);
    float4 gg = ((const float4*)g)[i];
    float4 bb = ((const float4*)b)[i];
    ushort4 o4;
    o4.x = f2b((v.x - mean) * rstd * gg.x + bb.x);
    o4.y = f2b((v.y - mean) * rstd * gg.y + bb.y);
    o4.z = f2b((v.z - mean) * rstd * gg.z + bb.z);
    o4.w = f2b((v.w - mean) * rstd * gg.w + bb.w);
    ((ushort4*)(out + (size_t)bt * D_))[i] = o4;
}

// ---------------- fp32 -> bf16 convert (no transpose) ----------------
__global__ __launch_bounds__(256) void conv_kernel(
        const float* __restrict__ s, bf16_t* __restrict__ d, int n4) {
    int i = blockIdx.x * 256 + threadIdx.x;
    if (i >= n4) return;
    float4 f = ((const float4*)s)[i];
    ushort4 u = make_ushort4(f2b(f.x), f2b(f.y), f2b(f.z), f2b(f.w));
    ((ushort4*)d)[i] = u;
}

// ------------- fp32 [K][N] -> bf16 [N][K] transpose-convert, z = layer -----
__global__ __launch_bounds__(256) void tconv_kernel(
        const float* __restrict__ src, bf16_t* __restrict__ dst, int K, int N) {
    size_t ls = (size_t)K * N;
    const float* s = src + blockIdx.z * ls;
    bf16_t* d = dst + blockIdx.z * ls;
    __shared__ float tile[32][33];
    int n0 = blockIdx.x * 32, k0 = blockIdx.y * 32;
    int c = threadIdx.x & 31, r8 = threadIdx.x >> 5;
    #pragma unroll
    for (int i = 0; i < 4; ++i) {
        int r = r8 + i * 8;
        tile[r][c] = s[(size_t)(k0 + r) * N + n0 + c];
    }
    __syncthreads();
    #pragma unroll
    for (int i = 0; i < 4; ++i) {
        int r = r8 + i * 8;
        d[(size_t)(n0 + r) * K + k0 + c] = __float2bfloat16(tile[c][r]);
    }
}

// ---------------- bf16 MFMA GEMM (m97 structure) ----------------
// C[M,N] = epi(A[M,K](bf16) @ Bt[N,K]^T + bias) (+res) ; 128x128 tile, BK=32
template<int ACT, bool OBF, bool RES, bool CONVB>
__global__ __launch_bounds__(256) void mm_kernel(
        const bf16_t* __restrict__ A,
        const bf16_t* __restrict__ Bt,   // [N][K] bf16 (unless CONVB)
        const float*  __restrict__ Bf,   // [N][K] fp32 (if CONVB)
        const float*  __restrict__ bias,
        const float*  __restrict__ res,
        void* __restrict__ Cout,
        int M, int N, int K)
{
    __shared__ __align__(16) unsigned short As[128 * 32];
    __shared__ __align__(16) unsigned short Bs[128 * 32];
    const int t    = threadIdx.x;
    const int row0 = blockIdx.y * 128;
    const int col0 = blockIdx.x * 128;
    const int lane = t & 63;
    const int wid  = t >> 6;
    const int wm   = (wid & 1) * 64;
    const int wn   = (wid >> 1) * 64;
    const int fr   = lane & 15;
    const int fq   = lane >> 4;

    f32x4 acc[4][4];
    #pragma unroll
    for (int m = 0; m < 4; ++m)
        #pragma unroll
        for (int n = 0; n < 4; ++n)
            acc[m][n] = (f32x4)(0.0f);

    const unsigned short* Ab  = (const unsigned short*)A;
    const unsigned short* Btb = (const unsigned short*)Bt;

    for (int k0 = 0; k0 < K; k0 += 32) {
        __syncthreads();
        {
            int c = t;
            gl16(Ab + (size_t)(row0 + (c >> 2)) * K + k0 + (c & 3) * 8, As + c * 8);
            c = t + 256;
            gl16(Ab + (size_t)(row0 + (c >> 2)) * K + k0 + (c & 3) * 8, As + c * 8);
        }
        if (!CONVB) {
            int c = t;
            gl16(Btb + (size_t)(col0 + (c >> 2)) * K + k0 + (c & 3) * 8, Bs + c * 8);
            c = t + 256;
            gl16(Btb + (size_t)(col0 + (c >> 2)) * K + k0 + (c & 3) * 8, Bs + c * 8);
        } else {
            #pragma unroll
            for (int i = 0; i < 2; ++i) {
                int c = t + i * 256;
                const float* sp = Bf + (size_t)(col0 + (c >> 2)) * K + k0 + (c & 3) * 8;
                float4 f0 = ((const float4*)sp)[0];
                float4 f1 = ((const float4*)sp)[1];
                short8 pk;
                pk[0] = f2b(f0.x); pk[1] = f2b(f0.y); pk[2] = f2b(f0.z); pk[3] = f2b(f0.w);
                pk[4] = f2b(f1.x); pk[5] = f2b(f1.y); pk[6] = f2b(f1.z); pk[7] = f2b(f1.w);
                *(short8*)(Bs + (size_t)c * 8) = pk;
            }
        }
        __syncthreads();

        short8 av[4], bv[4];
        #pragma unroll
        for (int m = 0; m < 4; ++m)
            av[m] = *(const short8*)(As + (wm + m * 16 + fr) * 32 + fq * 8);
        #pragma unroll
        for (int n = 0; n < 4; ++n)
            bv[n] = *(const short8*)(Bs + (wn + n * 16 + fr) * 32 + fq * 8);
        #pragma unroll
        for (int m = 0; m < 4; ++m)
            #pragma unroll
            for (int n = 0; n < 4; ++n)
                acc[m][n] = __builtin_amdgcn_mfma_f32_16x16x32_bf16(av[m], bv[n], acc[m][n], 0, 0, 0);
    }

    // epilogue: C row = row0+wm+m*16+fq*4+r, col = col0+wn+n*16+fr
    #pragma unroll
    for (int n = 0; n < 4; ++n) {
        int col = col0 + wn + n * 16 + fr;
        float bb = bias ? bias[col] : 0.0f;
        #pragma unroll
        for (int m = 0; m < 4; ++m) {
            int rbase = row0 + wm + m * 16 + fq * 4;
            #pragma unroll
            for (int r = 0; r < 4; ++r) {
                float v = acc[m][n][r] + bb;
                if (ACT == 1) v = gelu_exact(v);
                size_t off = (size_t)(rbase + r) * N + col;
                if (RES) v += res[off];
                if (OBF) ((bf16_t*)Cout)[off] = __float2bfloat16(v);
                else     ((float*)Cout)[off]  = v;
            }
        }
    }
}

// ---------------- flash attention, 64-row Q tile per block ----------------
// qkv bf16 [BT][3D]; y bf16 [BT][D]
__global__ __launch_bounds__(256) void flash_kernel(
        const bf16_t* __restrict__ qkv, bf16_t* __restrict__ y)
{
    __shared__ unsigned short Qs[64][68];  // [d][qr], prescaled by 1/8
    __shared__ float Ks[64][68];           // [d][j]
    __shared__ float Vs[64][68];           // [j][d]
    __shared__ float Ps[64][68];           // [qr][j]

    const int qt   = blockIdx.x;
    const int bh   = blockIdx.y;
    const int h    = bh & (H_ - 1);
    const int b    = bh >> 3;
    const int t    = threadIdx.x;
    const int qr   = t >> 2;
    const int quad = t & 3;
    const int q0   = qt * 64;
    const int j0   = quad * 16;
    const int d0   = quad * 16;

    const unsigned short* qkvb = (const unsigned short*)qkv;

    {   // stage Q transposed, scale by 0.125 (exact in bf16)
        const size_t base = (size_t)(b * T_ + q0) * (3 * D_) + h * DH_;
        #pragma unroll
        for (int i = 0; i < 4; ++i) {
            int c = t + i * 256;
            int row = c >> 4;
            int d4 = (c & 15) * 4;
            ushort4 u = *(const ushort4*)(qkvb + base + (size_t)row * (3 * D_) + d4);
            Qs[d4 + 0][row] = f2b(b2f(u.x) * 0.125f);
            Qs[d4 + 1][row] = f2b(b2f(u.y) * 0.125f);
            Qs[d4 + 2][row] = f2b(b2f(u.z) * 0.125f);
            Qs[d4 + 3][row] = f2b(b2f(u.w) * 0.125f);
        }
    }

    float mi = -INFINITY, li = 0.0f;
    float o[16];
    #pragma unroll
    for (int i = 0; i < 16; ++i) o[i] = 0.0f;

    for (int jt = 0; jt <= qt; ++jt) {
        __syncthreads();
        const size_t kbase = (size_t)(b * T_ + jt * 64) * (3 * D_) + D_ + h * DH_;
        const size_t vbase = kbase + D_;
        #pragma unroll
        for (int i = 0; i < 4; ++i) {
            int c = t + i * 256;
            int row = c >> 4;
            int d4 = (c & 15) * 4;
            ushort4 ku = *(const ushort4*)(qkvb + kbase + (size_t)row * (3 * D_) + d4);
            Ks[d4 + 0][row] = b2f(ku.x);
            Ks[d4 + 1][row] = b2f(ku.y);
            Ks[d4 + 2][row] = b2f(ku.z);
            Ks[d4 + 3][row] = b2f(ku.w);
            ushort4 vu = *(const ushort4*)(qkvb + vbase + (size_t)row * (3 * D_) + d4);
            *(float4*)&Vs[row][d4] = make_float4(b2f(vu.x), b2f(vu.y), b2f(vu.z), b2f(vu.w));
        }
        __syncthreads();

        float s[16];
        #pragma unroll
        for (int i = 0; i < 16; ++i) s[i] = 0.0f;
        #pragma unroll 4
        for (int d = 0; d < 64; ++d) {
            float qv = b2f(Qs[d][qr]);
            const float4 k0v = *(const float4*)&Ks[d][j0];
            const float4 k1v = *(const float4*)&Ks[d][j0 + 4];
            const float4 k2v = *(const float4*)&Ks[d][j0 + 8];
            const float4 k3v = *(const float4*)&Ks[d][j0 + 12];
            s[0]  = fmaf(qv, k0v.x, s[0]);  s[1]  = fmaf(qv, k0v.y, s[1]);
            s[2]  = fmaf(qv, k0v.z, s[2]);  s[3]  = fmaf(qv, k0v.w, s[3]);
            s[4]  = fmaf(qv, k1v.x, s[4]);  s[5]  = fmaf(qv, k1v.y, s[5]);
            s[6]  = fmaf(qv, k1v.z, s[6]);  s[7]  = fmaf(qv, k1v.w, s[7]);
            s[8]  = fmaf(qv, k2v.x, s[8]);  s[9]  = fmaf(qv, k2v.y, s[9]);
            s[10] = fmaf(qv, k2v.z, s[10]); s[11] = fmaf(qv, k2v.w, s[11]);
            s[12] = fmaf(qv, k3v.x, s[12]); s[13] = fmaf(qv, k3v.y, s[13]);
            s[14] = fmaf(qv, k3v.z, s[14]); s[15] = fmaf(qv, k3v.w, s[15]);
        }
        if (jt == qt) {
            #pragma unroll
            for (int i = 0; i < 16; ++i)
                if (j0 + i > qr) s[i] = -INFINITY;
        }
        float tm = s[0];
        #pragma unroll
        for (int i = 1; i < 16; ++i) tm = fmaxf(tm, s[i]);
        tm = fmaxf(tm, __shfl_xor(tm, 1));
        tm = fmaxf(tm, __shfl_xor(tm, 2));
        float mnew = fmaxf(mi, tm);
        float corr = __expf(mi - mnew);
        float tsum = 0.0f;
        #pragma unroll
        for (int i = 0; i < 16; ++i) {
            float p = __expf(s[i] - mnew);
            Ps[qr][j0 + i] = p;
            tsum += p;
        }
        tsum += __shfl_xor(tsum, 1);
        tsum += __shfl_xor(tsum, 2);
        li = li * corr + tsum;
        mi = mnew;
        #pragma unroll
        for (int i = 0; i < 16; ++i) o[i] *= corr;

        #pragma unroll 4
        for (int j = 0; j < 64; ++j) {
            float pv = Ps[qr][j];
            const float4 v0 = *(const float4*)&Vs[j][d0];
            const float4 v1 = *(const float4*)&Vs[j][d0 + 4];
            const float4 v2 = *(const float4*)&Vs[j][d0 + 8];
            const float4 v3 = *(const float4*)&Vs[j][d0 + 12];
            o[0]  = fmaf(pv, v0.x, o[0]);  o[1]  = fmaf(pv, v0.y, o[1]);
            o[2]  = fmaf(pv, v0.z, o[2]);  o[3]  = fmaf(pv, v0.w, o[3]);
            o[4]  = fmaf(pv, v1.x, o[4]);  o[5]  = fmaf(pv, v1.y, o[5]);
            o[6]  = fmaf(pv, v1.z, o[6]);  o[7]  = fmaf(pv, v1.w, o[7]);
            o[8]  = fmaf(pv, v2.x, o[8]);  o[9]  = fmaf(pv, v2.y, o[9]);
            o[10] = fmaf(pv, v2.z, o[10]); o[11] = fmaf(pv, v2.w, o[11]);
            o[12] = fmaf(pv, v3.x, o[12]); o[13] = fmaf(pv, v3.y, o[13]);
            o[14] = fmaf(pv, v3.z, o[14]); o[15] = fmaf(pv, v3.w, o[15]);
        }
    }

    float inv = 1.0f / li;
    unsigned short* yb = (unsigned short*)y;
    size_t yoff = (size_t)(b * T_ + q0 + qr) * D_ + h * DH_ + d0;
    #pragma unroll
    for (int g2 = 0; g2 < 4; ++g2) {
        ushort4 u = make_ushort4(f2b(o[g2*4+0] * inv), f2b(o[g2*4+1] * inv),
                                 f2b(o[g2*4+2] * inv), f2b(o[g2*4+3] * inv));
        *(ushort4*)(yb + yoff + g2 * 4) = u;
    }
}

// ---------------- launcher ----------------
extern "C" void kernel_launch(void* const* d_in, const int* in_sizes, int n_in,
                              void* d_out, int out_size, void* d_ws, size_t ws_size,
                              hipStream_t stream) {
    const int*   idx   = (const int*)  d_in[0];
    const float* wte   = (const float*)d_in[1];
    const float* wpe   = (const float*)d_in[2];
    const float* ln1_g = (const float*)d_in[3];
    const float* ln1_b = (const float*)d_in[4];
    const float* w_qkv = (const float*)d_in[5];
    const float* b_qkv = (const float*)d_in[6];
    const float* w_ao  = (const float*)d_in[7];
    const float* b_ao  = (const float*)d_in[8];
    const float* ln2_g = (const float*)d_in[9];
    const float* ln2_b = (const float*)d_in[10];
    const float* w_fc  = (const float*)d_in[11];
    const float* b_fc  = (const float*)d_in[12];
    const float* w_pr  = (const float*)d_in[13];
    const float* b_pr  = (const float*)d_in[14];
    const float* lnf_g = (const float*)d_in[15];
    const float* lnf_b = (const float*)d_in[16];
    float* outf = (float*)d_out;

    // scratch carved from d_out (dead before the head GEMM overwrites it)
    char* base = (char*)d_out;
    size_t off = 0;
    auto alloc = [&](size_t bytes) {
        void* p = base + off;
        off += (bytes + 255) & ~(size_t)255;
        return p;
    };
    bf16_t* wqkvT = (bf16_t*)alloc((size_t)L_ * 3 * D_ * D_ * 2);  // [l][1536][512]
    bf16_t* waoT  = (bf16_t*)alloc((size_t)L_ * D_ * D_ * 2);      // [l][512][512]
    bf16_t* wfcT  = (bf16_t*)alloc((size_t)L_ * DFF_ * D_ * 2);    // [l][2048][512]
    bf16_t* wprT  = (bf16_t*)alloc((size_t)L_ * D_ * DFF_ * 2);    // [l][512][2048]
    bf16_t* qkvb  = (bf16_t*)alloc((size_t)BT_ * 3 * D_ * 2);
    bf16_t* yb    = (bf16_t*)alloc((size_t)BT_ * D_ * 2);
    bf16_t* hab   = (bf16_t*)alloc((size_t)BT_ * D_ * 2);
    bf16_t* fcb   = (bf16_t*)alloc((size_t)BT_ * DFF_ * 2);
    float*  xb    = (float*) alloc((size_t)BT_ * D_ * 4);

    // ws: final-LN output must survive the head GEMM (which clobbers d_out)
    bf16_t* hfin = (bf16_t*)d_ws;
    size_t hbytes = ((size_t)BT_ * D_ * 2 + 255) & ~(size_t)255;
    bool wte_ws = ws_size >= hbytes + (size_t)V_ * D_ * 2 + 256;
    bf16_t* wteb = wte_ws ? (bf16_t*)((char*)d_ws + hbytes) : nullptr;

    // weight conversions
    if (wte_ws)
        conv_kernel<<<(V_ * D_ / 4 + 255) / 256, 256, 0, stream>>>(wte, wteb, V_ * D_ / 4);
    tconv_kernel<<<dim3(3 * D_ / 32, D_ / 32, L_), 256, 0, stream>>>(w_qkv, wqkvT, D_, 3 * D_);
    tconv_kernel<<<dim3(D_ / 32, D_ / 32, L_), 256, 0, stream>>>(w_ao, waoT, D_, D_);
    tconv_kernel<<<dim3(DFF_ / 32, D_ / 32, L_), 256, 0, stream>>>(w_fc, wfcT, D_, DFF_);
    tconv_kernel<<<dim3(D_ / 32, DFF_ / 32, L_), 256, 0, stream>>>(w_pr, wprT, DFF_, D_);

    embed_kernel<<<BT_, 128, 0, stream>>>(idx, wte, wpe, xb);

    for (int l = 0; l < L_; ++l) {
        ln_kernel<<<BT_, 128, 0, stream>>>(xb, ln1_g + l * D_, ln1_b + l * D_, hab);
        mm_kernel<0, true, false, false><<<dim3(12, 64), 256, 0, stream>>>(
            hab, wqkvT + (size_t)l * 3 * D_ * D_, nullptr, b_qkv + (size_t)l * 3 * D_,
            nullptr, qkvb, BT_, 3 * D_, D_);
        flash_kernel<<<dim3(16, 64), 256, 0, stream>>>(qkvb, yb);
        mm_kernel<0, false, true, false><<<dim3(4, 64), 256, 0, stream>>>(
            yb, waoT + (size_t)l * D_ * D_, nullptr, b_ao + (size_t)l * D_,
            xb, xb, BT_, D_, D_);
        ln_kernel<<<BT_, 128, 0, stream>>>(xb, ln2_g + l * D_, ln2_b + l * D_, hab);
        mm_kernel<1, true, false, false><<<dim3(16, 64), 256, 0, stream>>>(
            hab, wfcT + (size_t)l * DFF_ * D_, nullptr, b_fc + (size_t)l * DFF_,
            nullptr, fcb, BT_, DFF_, D_);
        mm_kernel<0, false, true, false><<<dim3(4, 64), 256, 0, stream>>>(
            fcb, wprT + (size_t)l * D_ * DFF_, nullptr, b_pr + (size_t)l * D_,
            xb, xb, BT_, D_, DFF_);
    }

    ln_kernel<<<BT_, 128, 0, stream>>>(xb, lnf_g, lnf_b, hfin);
    if (wte_ws)
        mm_kernel<0, false, false, false><<<dim3(V_ / 128, BT_ / 128), 256, 0, stream>>>(
            hfin, wteb, nullptr, nullptr, nullptr, outf, BT_, V_, D_);
    else
        mm_kernel<0, false, false, true><<<dim3(V_ / 128, BT_ / 128), 256, 0, stream>>>(
            hfin, nullptr, wte, nullptr, nullptr, outf, BT_, V_, D_);
}

// Round 3
// 2012.202 us; speedup vs baseline: 9.1047x; 1.7769x over previous
//
#include <hip/hip_runtime.h>
#include <hip/hip_bf16.h>
#include <math.h>

#define V_   32000
#define D_   512
#define L_   6
#define H_   8
#define DH_  64
#define DFF_ 2048
#define B_   8
#define T_   1024
#define BT_  (B_*T_)

typedef __attribute__((ext_vector_type(4))) float f32x4;
typedef __attribute__((ext_vector_type(8))) short short8;
using bf16_t = __hip_bfloat16;

__device__ __forceinline__ float b2f(unsigned short u) {
    union { unsigned int i; float f; } v; v.i = ((unsigned int)u) << 16; return v.f;
}
__device__ __forceinline__ unsigned short f2b(float f) {
    bf16_t h = __float2bfloat16(f);
    return *reinterpret_cast<unsigned short*>(&h);
}
__device__ __forceinline__ void gl16(const void* g, void* l) {
    __builtin_amdgcn_global_load_lds((const __attribute__((address_space(1))) void*)g,
                                     (__attribute__((address_space(3))) void*)l, 16, 0, 0);
}
__device__ __forceinline__ float gelu_exact(float v) {
    return 0.5f * v * (1.0f + erff(v * 0.70710678118654752f));
}

// ---------------- embedding: x = wte[idx] + wpe[t] (fp32 residual) --------
__global__ __launch_bounds__(128) void embed_kernel(
        const int* __restrict__ idx, const float* __restrict__ wte,
        const float* __restrict__ wpe, float* __restrict__ x) {
    int bt = blockIdx.x;
    int t  = bt & (T_ - 1);
    int tok = idx[bt];
    const float4* wr = (const float4*)(wte + (size_t)tok * D_);
    const float4* pr = (const float4*)(wpe + (size_t)t * D_);
    float4* xr = (float4*)(x + (size_t)bt * D_);
    int i = threadIdx.x;
    float4 a = wr[i], b = pr[i];
    xr[i] = make_float4(a.x + b.x, a.y + b.y, a.z + b.z, a.w + b.w);
}

// ---------------- layernorm fp32 in -> bf16 out ----------------
__global__ __launch_bounds__(128) void ln_kernel(
        const float* __restrict__ x, const float* __restrict__ g,
        const float* __restrict__ b, bf16_t* __restrict__ out) {
    int bt = blockIdx.x;
    int i  = threadIdx.x;
    float4 v = ((const float4*)(x + (size_t)bt * D_))[i];
    float s  = v.x + v.y + v.z + v.w;
    float sq = v.x*v.x + v.y*v.y + v.z*v.z + v.w*v.w;
    #pragma unroll
    for (int o = 32; o > 0; o >>= 1) {
        s  += __shfl_down(s,  o);
        sq += __shfl_down(sq, o);
    }
    __shared__ float ss[2], ssq[2];
    if ((i & 63) == 0) { ss[i >> 6] = s; ssq[i >> 6] = sq; }
    __syncthreads();
    float mean = (ss[0] + ss[1]) * (1.0f / D_);
    float var  = (ssq[0] + ssq[1]) * (1.0f / D_) - mean * mean;
    float rstd = rsqrtf(var + 1e-5f);
    float4 gg = ((const float4*)g)[i];
    float4 bb = ((const float4*)b)[i];
    ushort4 o4;
    o4.x = f2b((v.x - mean) * rstd * gg.x + bb.x);
    o4.y = f2b((v.y - mean) * rstd * gg.y + bb.y);
    o4.z = f2b((v.z - mean) * rstd * gg.z + bb.z);
    o4.w = f2b((v.w - mean) * rstd * gg.w + bb.w);
    ((ushort4*)(out + (size_t)bt * D_))[i] = o4;
}

// ---------------- fp32 -> bf16 convert (no transpose) ----------------
__global__ __launch_bounds__(256) void conv_kernel(
        const float* __restrict__ s, bf16_t* __restrict__ d, int n4) {
    int i = blockIdx.x * 256 + threadIdx.x;
    if (i >= n4) return;
    float4 f = ((const float4*)s)[i];
    ushort4 u = make_ushort4(f2b(f.x), f2b(f.y), f2b(f.z), f2b(f.w));
    ((ushort4*)d)[i] = u;
}

// ------------- fp32 [K][N] -> bf16 [N][K] transpose-convert, z = layer -----
__global__ __launch_bounds__(256) void tconv_kernel(
        const float* __restrict__ src, bf16_t* __restrict__ dst, int K, int N) {
    size_t ls = (size_t)K * N;
    const float* s = src + blockIdx.z * ls;
    bf16_t* d = dst + blockIdx.z * ls;
    __shared__ float tile[32][33];
    int n0 = blockIdx.x * 32, k0 = blockIdx.y * 32;
    int c = threadIdx.x & 31, r8 = threadIdx.x >> 5;
    #pragma unroll
    for (int i = 0; i < 4; ++i) {
        int r = r8 + i * 8;
        tile[r][c] = s[(size_t)(k0 + r) * N + n0 + c];
    }
    __syncthreads();
    #pragma unroll
    for (int i = 0; i < 4; ++i) {
        int r = r8 + i * 8;
        d[(size_t)(n0 + r) * K + k0 + c] = __float2bfloat16(tile[c][r]);
    }
}

// ---------------- bf16 MFMA GEMM (m97 structure, XCD-swizzled 1D grid) -----
// C[M,N] = epi(A[M,K](bf16) @ Bt[N,K]^T + bias) (+res) ; 128x128 tile, BK=32
template<int ACT, bool OBF, bool RES, bool CONVB>
__global__ __launch_bounds__(256) void mm_kernel(
        const bf16_t* __restrict__ A,
        const bf16_t* __restrict__ Bt,   // [N][K] bf16 (unless CONVB)
        const float*  __restrict__ Bf,   // [N][K] fp32 (if CONVB)
        const float*  __restrict__ bias,
        const float*  __restrict__ res,
        void* __restrict__ Cout,
        int M, int N, int K)
{
    __shared__ __align__(16) unsigned short As[128 * 32];
    __shared__ __align__(16) unsigned short Bs[128 * 32];
    // bijective XCD swizzle (m204) + column-major tile order (M fast)
    const int nwg = gridDim.x;
    const int orig = blockIdx.x;
    const int q8 = nwg >> 3, r8 = nwg & 7;
    const int xcd = orig & 7, lin = orig >> 3;
    const int wg = (xcd < r8) ? xcd * (q8 + 1) + lin
                              : r8 * (q8 + 1) + (xcd - r8) * q8 + lin;
    const int gym = M >> 7;
    const int by = wg % gym;
    const int bx = wg / gym;

    const int t    = threadIdx.x;
    const int row0 = by * 128;
    const int col0 = bx * 128;
    const int lane = t & 63;
    const int wid  = t >> 6;
    const int wm   = (wid & 1) * 64;
    const int wn   = (wid >> 1) * 64;
    const int fr   = lane & 15;
    const int fq   = lane >> 4;

    f32x4 acc[4][4];
    #pragma unroll
    for (int m = 0; m < 4; ++m)
        #pragma unroll
        for (int n = 0; n < 4; ++n)
            acc[m][n] = (f32x4)(0.0f);

    const unsigned short* Ab  = (const unsigned short*)A;
    const unsigned short* Btb = (const unsigned short*)Bt;

    for (int k0 = 0; k0 < K; k0 += 32) {
        __syncthreads();
        {
            int c = t;
            gl16(Ab + (size_t)(row0 + (c >> 2)) * K + k0 + (c & 3) * 8, As + c * 8);
            c = t + 256;
            gl16(Ab + (size_t)(row0 + (c >> 2)) * K + k0 + (c & 3) * 8, As + c * 8);
        }
        if (!CONVB) {
            int c = t;
            gl16(Btb + (size_t)(col0 + (c >> 2)) * K + k0 + (c & 3) * 8, Bs + c * 8);
            c = t + 256;
            gl16(Btb + (size_t)(col0 + (c >> 2)) * K + k0 + (c & 3) * 8, Bs + c * 8);
        } else {
            #pragma unroll
            for (int i = 0; i < 2; ++i) {
                int c = t + i * 256;
                const float* sp = Bf + (size_t)(col0 + (c >> 2)) * K + k0 + (c & 3) * 8;
                float4 f0 = ((const float4*)sp)[0];
                float4 f1 = ((const float4*)sp)[1];
                short8 pk;
                pk[0] = f2b(f0.x); pk[1] = f2b(f0.y); pk[2] = f2b(f0.z); pk[3] = f2b(f0.w);
                pk[4] = f2b(f1.x); pk[5] = f2b(f1.y); pk[6] = f2b(f1.z); pk[7] = f2b(f1.w);
                *(short8*)(Bs + (size_t)c * 8) = pk;
            }
        }
        __syncthreads();

        short8 av[4], bv[4];
        #pragma unroll
        for (int m = 0; m < 4; ++m)
            av[m] = *(const short8*)(As + (wm + m * 16 + fr) * 32 + fq * 8);
        #pragma unroll
        for (int n = 0; n < 4; ++n)
            bv[n] = *(const short8*)(Bs + (wn + n * 16 + fr) * 32 + fq * 8);
        #pragma unroll
        for (int m = 0; m < 4; ++m)
            #pragma unroll
            for (int n = 0; n < 4; ++n)
                acc[m][n] = __builtin_amdgcn_mfma_f32_16x16x32_bf16(av[m], bv[n], acc[m][n], 0, 0, 0);
    }

    // epilogue: C row = row0+wm+m*16+fq*4+r, col = col0+wn+n*16+fr
    #pragma unroll
    for (int n = 0; n < 4; ++n) {
        int col = col0 + wn + n * 16 + fr;
        float bb = bias ? bias[col] : 0.0f;
        #pragma unroll
        for (int m = 0; m < 4; ++m) {
            int rbase = row0 + wm + m * 16 + fq * 4;
            #pragma unroll
            for (int r = 0; r < 4; ++r) {
                float v = acc[m][n][r] + bb;
                if (ACT == 1) v = gelu_exact(v);
                size_t off = (size_t)(rbase + r) * N + col;
                if (RES) v += res[off];
                if (OBF) ((bf16_t*)Cout)[off] = __float2bfloat16(v);
                else     ((float*)Cout)[off]  = v;
            }
        }
    }
}

// ---------------- MFMA flash attention, 64-row Q tile per block ------------
// qkv bf16 [BT][3D]; y bf16 [BT][D]; 256 threads = 4 waves, wave w owns
// q rows [qt*64 + w*16, +16). Fragment maps as validated in mm_kernel:
//   A: row=lane&15, k=(lane>>4)*8+e ; Bt: col=lane&15 ; C: row=(lane>>4)*4+r, col=lane&15
__global__ __launch_bounds__(256) void flash_kernel(
        const bf16_t* __restrict__ qkv, bf16_t* __restrict__ y)
{
    __shared__ __align__(16) unsigned short Ks[64][72];   // [j][d]
    __shared__ __align__(16) unsigned short Vt[64][72];   // [d][j]
    __shared__ __align__(16) unsigned short Pls[64][72];  // [q][j]

    const int qt = blockIdx.x;
    const int bh = blockIdx.y;
    const int h  = bh & (H_ - 1);
    const int b  = bh >> 3;
    const int t  = threadIdx.x;
    const int lane = t & 63;
    const int w    = t >> 6;
    const int fr   = lane & 15;
    const int fq   = lane >> 4;

    const unsigned short* qkvb = (const unsigned short*)qkv;

    // Q fragments in registers (A operand), rows = qt*64 + w*16 + fr
    short8 avq[2];
    {
        const unsigned short* qrow = qkvb +
            (size_t)(b * T_ + qt * 64 + w * 16 + fr) * (3 * D_) + h * DH_;
        avq[0] = *(const short8*)(qrow + fq * 8);
        avq[1] = *(const short8*)(qrow + 32 + fq * 8);
    }

    float mi[4], li[4];
    f32x4 o[4];                       // O acc: col d = db*16+fr, row = fq*4+r
    #pragma unroll
    for (int r = 0; r < 4; ++r) { mi[r] = -INFINITY; li[r] = 0.0f; o[r] = (f32x4)(0.0f); }
    f32x4 o2[4];
    #pragma unroll
    for (int r = 0; r < 4; ++r) o2[r] = (f32x4)(0.0f);
    // o[db] is f32x4 over r — reorganize: use o[db][r]; declared as 4 vectors:
    f32x4 oacc[4];
    #pragma unroll
    for (int d = 0; d < 4; ++d) oacc[d] = (f32x4)(0.0f);
    (void)o; (void)o2;

    for (int jt = 0; jt <= qt; ++jt) {
        __syncthreads();
        // stage K [j][d] and V transposed [d][j]
        {
            int j = t >> 2, seg = t & 3;
            const unsigned short* krow = qkvb +
                (size_t)(b * T_ + jt * 64 + j) * (3 * D_) + D_ + h * DH_ + seg * 16;
            *(short8*)&Ks[j][seg * 16]     = *(const short8*)(krow);
            *(short8*)&Ks[j][seg * 16 + 8] = *(const short8*)(krow + 8);
            const unsigned short* vrow = krow + D_;
            #pragma unroll
            for (int d4 = 0; d4 < 4; ++d4) {
                ushort4 u = *(const ushort4*)(vrow + d4 * 4);
                int d = seg * 16 + d4 * 4;
                Vt[d + 0][j] = u.x; Vt[d + 1][j] = u.y;
                Vt[d + 2][j] = u.z; Vt[d + 3][j] = u.w;
            }
        }
        __syncthreads();

        // S = Q @ K^T for this wave's 16 q-rows x 64 j
        f32x4 s[4];
        #pragma unroll
        for (int jb = 0; jb < 4; ++jb) s[jb] = (f32x4)(0.0f);
        #pragma unroll
        for (int ks = 0; ks < 2; ++ks) {
            #pragma unroll
            for (int jb = 0; jb < 4; ++jb) {
                short8 bv = *(const short8*)(&Ks[jb * 16 + fr][ks * 32 + fq * 8]);
                s[jb] = __builtin_amdgcn_mfma_f32_16x16x32_bf16(avq[ks], bv, s[jb], 0, 0, 0);
            }
        }

        // scale + causal mask; rows = fq*4+r, cols = jb*16+fr
        float sv[4][4];
        #pragma unroll
        for (int jb = 0; jb < 4; ++jb)
            #pragma unroll
            for (int r = 0; r < 4; ++r)
                sv[jb][r] = s[jb][r] * 0.125f;
        if (jt == qt) {
            #pragma unroll
            for (int jb = 0; jb < 4; ++jb) {
                int j_loc = jb * 16 + fr;
                #pragma unroll
                for (int r = 0; r < 4; ++r) {
                    int q_loc = w * 16 + fq * 4 + r;
                    if (jt * 64 + j_loc > qt * 64 + q_loc - w * 16 + w * 16) {}
                    if (j_loc > (fq * 4 + r) + (w * 16) - (w * 16) + (q_loc - q_loc)) {}
                }
            }
            // proper mask: j_global > q_global  <=>  jb*16+fr > w*16+fq*4+r (same 64-tile)
            #pragma unroll
            for (int jb = 0; jb < 4; ++jb) {
                int j_loc = jb * 16 + fr;
                #pragma unroll
                for (int r = 0; r < 4; ++r) {
                    int q_loc = w * 16 + fq * 4 + r;
                    if (j_loc > q_loc) sv[jb][r] = -INFINITY;
                }
            }
        }

        // online softmax: row stats across jb (in-reg) then fr lanes (shfl)
        #pragma unroll
        for (int r = 0; r < 4; ++r) {
            float tm = fmaxf(fmaxf(sv[0][r], sv[1][r]), fmaxf(sv[2][r], sv[3][r]));
            tm = fmaxf(tm, __shfl_xor(tm, 1));
            tm = fmaxf(tm, __shfl_xor(tm, 2));
            tm = fmaxf(tm, __shfl_xor(tm, 4));
            tm = fmaxf(tm, __shfl_xor(tm, 8));
            float mnew = fmaxf(mi[r], tm);
            float corr = __expf(mi[r] - mnew);
            float tsum = 0.0f;
            #pragma unroll
            for (int jb = 0; jb < 4; ++jb) {
                float p = __expf(sv[jb][r] - mnew);
                sv[jb][r] = p;
                tsum += p;
            }
            tsum += __shfl_xor(tsum, 1);
            tsum += __shfl_xor(tsum, 2);
            tsum += __shfl_xor(tsum, 4);
            tsum += __shfl_xor(tsum, 8);
            li[r] = li[r] * corr + tsum;
            mi[r] = mnew;
            #pragma unroll
            for (int db = 0; db < 4; ++db) oacc[db][r] *= corr;
        }

        // P -> LDS (wave-private rows), then PV
        #pragma unroll
        for (int jb = 0; jb < 4; ++jb)
            #pragma unroll
            for (int r = 0; r < 4; ++r)
                Pls[w * 16 + fq * 4 + r][jb * 16 + fr] = f2b(sv[jb][r]);
        __syncthreads();

        #pragma unroll
        for (int ks = 0; ks < 2; ++ks) {
            short8 ap = *(const short8*)(&Pls[w * 16 + fr][ks * 32 + fq * 8]);
            #pragma unroll
            for (int db = 0; db < 4; ++db) {
                short8 bv = *(const short8*)(&Vt[db * 16 + fr][ks * 32 + fq * 8]);
                oacc[db] = __builtin_amdgcn_mfma_f32_16x16x32_bf16(ap, bv, oacc[db], 0, 0, 0);
            }
        }
    }

    // write y: row = qt*64 + w*16 + fq*4 + r, col = h*64 + db*16 + fr
    unsigned short* yb = (unsigned short*)y;
    #pragma unroll
    for (int r = 0; r < 4; ++r) {
        float inv = 1.0f / li[r];
        size_t row = (size_t)(b * T_ + qt * 64 + w * 16 + fq * 4 + r);
        #pragma unroll
        for (int db = 0; db < 4; ++db)
            yb[row * D_ + h * DH_ + db * 16 + fr] = f2b(oacc[db][r] * inv);
    }
}

// ---------------- launcher ----------------
extern "C" void kernel_launch(void* const* d_in, const int* in_sizes, int n_in,
                              void* d_out, int out_size, void* d_ws, size_t ws_size,
                              hipStream_t stream) {
    const int*   idx   = (const int*)  d_in[0];
    const float* wte   = (const float*)d_in[1];
    const float* wpe   = (const float*)d_in[2];
    const float* ln1_g = (const float*)d_in[3];
    const float* ln1_b = (const float*)d_in[4];
    const float* w_qkv = (const float*)d_in[5];
    const float* b_qkv = (const float*)d_in[6];
    const float* w_ao  = (const float*)d_in[7];
    const float* b_ao  = (const float*)d_in[8];
    const float* ln2_g = (const float*)d_in[9];
    const float* ln2_b = (const float*)d_in[10];
    const float* w_fc  = (const float*)d_in[11];
    const float* b_fc  = (const float*)d_in[12];
    const float* w_pr  = (const float*)d_in[13];
    const float* b_pr  = (const float*)d_in[14];
    const float* lnf_g = (const float*)d_in[15];
    const float* lnf_b = (const float*)d_in[16];
    float* outf = (float*)d_out;

    // scratch carved from d_out (dead before the head GEMM overwrites it)
    char* base = (char*)d_out;
    size_t off = 0;
    auto alloc = [&](size_t bytes) {
        void* p = base + off;
        off += (bytes + 255) & ~(size_t)255;
        return p;
    };
    bf16_t* wqkvT = (bf16_t*)alloc((size_t)L_ * 3 * D_ * D_ * 2);
    bf16_t* waoT  = (bf16_t*)alloc((size_t)L_ * D_ * D_ * 2);
    bf16_t* wfcT  = (bf16_t*)alloc((size_t)L_ * DFF_ * D_ * 2);
    bf16_t* wprT  = (bf16_t*)alloc((size_t)L_ * D_ * DFF_ * 2);
    bf16_t* qkvb  = (bf16_t*)alloc((size_t)BT_ * 3 * D_ * 2);
    bf16_t* yb    = (bf16_t*)alloc((size_t)BT_ * D_ * 2);
    bf16_t* hab   = (bf16_t*)alloc((size_t)BT_ * D_ * 2);
    bf16_t* fcb   = (bf16_t*)alloc((size_t)BT_ * DFF_ * 2);
    float*  xb    = (float*) alloc((size_t)BT_ * D_ * 4);

    // ws: final-LN output must survive the head GEMM (which clobbers d_out)
    bf16_t* hfin = (bf16_t*)d_ws;
    size_t hbytes = ((size_t)BT_ * D_ * 2 + 255) & ~(size_t)255;
    bool wte_ws = ws_size >= hbytes + (size_t)V_ * D_ * 2 + 256;
    bf16_t* wteb = wte_ws ? (bf16_t*)((char*)d_ws + hbytes) : nullptr;

    if (wte_ws)
        conv_kernel<<<(V_ * D_ / 4 + 255) / 256, 256, 0, stream>>>(wte, wteb, V_ * D_ / 4);
    tconv_kernel<<<dim3(3 * D_ / 32, D_ / 32, L_), 256, 0, stream>>>(w_qkv, wqkvT, D_, 3 * D_);
    tconv_kernel<<<dim3(D_ / 32, D_ / 32, L_), 256, 0, stream>>>(w_ao, waoT, D_, D_);
    tconv_kernel<<<dim3(DFF_ / 32, D_ / 32, L_), 256, 0, stream>>>(w_fc, wfcT, D_, DFF_);
    tconv_kernel<<<dim3(D_ / 32, DFF_ / 32, L_), 256, 0, stream>>>(w_pr, wprT, DFF_, D_);

    embed_kernel<<<BT_, 128, 0, stream>>>(idx, wte, wpe, xb);

    for (int l = 0; l < L_; ++l) {
        ln_kernel<<<BT_, 128, 0, stream>>>(xb, ln1_g + l * D_, ln1_b + l * D_, hab);
        mm_kernel<0, true, false, false><<<12 * 64, 256, 0, stream>>>(
            hab, wqkvT + (size_t)l * 3 * D_ * D_, nullptr, b_qkv + (size_t)l * 3 * D_,
            nullptr, qkvb, BT_, 3 * D_, D_);
        flash_kernel<<<dim3(16, 64), 256, 0, stream>>>(qkvb, yb);
        mm_kernel<0, false, true, false><<<4 * 64, 256, 0, stream>>>(
            yb, waoT + (size_t)l * D_ * D_, nullptr, b_ao + (size_t)l * D_,
            xb, xb, BT_, D_, D_);
        ln_kernel<<<BT_, 128, 0, stream>>>(xb, ln2_g + l * D_, ln2_b + l * D_, hab);
        mm_kernel<1, true, false, false><<<16 * 64, 256, 0, stream>>>(
            hab, wfcT + (size_t)l * DFF_ * D_, nullptr, b_fc + (size_t)l * DFF_,
            nullptr, fcb, BT_, DFF_, D_);
        mm_kernel<0, false, true, false><<<4 * 64, 256, 0, stream>>>(
            fcb, wprT + (size_t)l * D_ * DFF_, nullptr, b_pr + (size_t)l * D_,
            xb, xb, BT_, D_, DFF_);
    }

    ln_kernel<<<BT_, 128, 0, stream>>>(xb, lnf_g, lnf_b, hfin);
    if (wte_ws)
        mm_kernel<0, false, false, false><<<250 * 64, 256, 0, stream>>>(
            hfin, wteb, nullptr, nullptr, nullptr, outf, BT_, V_, D_);
    else
        mm_kernel<0, false, false, true><<<250 * 64, 256, 0, stream>>>(
            hfin, nullptr, wte, nullptr, nullptr, outf, BT_, V_, D_);
}

// Round 4
// 1797.009 us; speedup vs baseline: 10.1950x; 1.1198x over previous
//
#include <hip/hip_runtime.h>
#include <hip/hip_bf16.h>
#include <math.h>

#define V_   32000
#define D_   512
#define L_   6
#define H_   8
#define DH_  64
#define DFF_ 2048
#define B_   8
#define T_   1024
#define BT_  (B_*T_)

typedef __attribute__((ext_vector_type(4))) float f32x4;
typedef __attribute__((ext_vector_type(8))) short short8;
using bf16_t = __hip_bfloat16;

__device__ __forceinline__ float b2f(unsigned short u) {
    union { unsigned int i; float f; } v; v.i = ((unsigned int)u) << 16; return v.f;
}
__device__ __forceinline__ unsigned short f2b(float f) {
    bf16_t h = __float2bfloat16(f);
    return *reinterpret_cast<unsigned short*>(&h);
}
__device__ __forceinline__ void gl16(const void* g, void* l) {
    __builtin_amdgcn_global_load_lds((const __attribute__((address_space(1))) void*)g,
                                     (__attribute__((address_space(3))) void*)l, 16, 0, 0);
}
__device__ __forceinline__ float gelu_exact(float v) {
    return 0.5f * v * (1.0f + erff(v * 0.70710678118654752f));
}

// ---------------- embedding: x = wte[idx] + wpe[t] (fp32 residual) --------
__global__ __launch_bounds__(128) void embed_kernel(
        const int* __restrict__ idx, const float* __restrict__ wte,
        const float* __restrict__ wpe, float* __restrict__ x) {
    int bt = blockIdx.x;
    int t  = bt & (T_ - 1);
    int tok = idx[bt];
    const float4* wr = (const float4*)(wte + (size_t)tok * D_);
    const float4* pr = (const float4*)(wpe + (size_t)t * D_);
    float4* xr = (float4*)(x + (size_t)bt * D_);
    int i = threadIdx.x;
    float4 a = wr[i], b = pr[i];
    xr[i] = make_float4(a.x + b.x, a.y + b.y, a.z + b.z, a.w + b.w);
}

// ---------------- layernorm fp32 in -> bf16 out ----------------
__global__ __launch_bounds__(128) void ln_kernel(
        const float* __restrict__ x, const float* __restrict__ g,
        const float* __restrict__ b, bf16_t* __restrict__ out) {
    int bt = blockIdx.x;
    int i  = threadIdx.x;
    float4 v = ((const float4*)(x + (size_t)bt * D_))[i];
    float s  = v.x + v.y + v.z + v.w;
    float sq = v.x*v.x + v.y*v.y + v.z*v.z + v.w*v.w;
    #pragma unroll
    for (int o = 32; o > 0; o >>= 1) {
        s  += __shfl_down(s,  o);
        sq += __shfl_down(sq, o);
    }
    __shared__ float ss[2], ssq[2];
    if ((i & 63) == 0) { ss[i >> 6] = s; ssq[i >> 6] = sq; }
    __syncthreads();
    float mean = (ss[0] + ss[1]) * (1.0f / D_);
    float var  = (ssq[0] + ssq[1]) * (1.0f / D_) - mean * mean;
    float rstd = rsqrtf(var + 1e-5f);
    float4 gg = ((const float4*)g)[i];
    float4 bb = ((const float4*)b)[i];
    ushort4 o4;
    o4.x = f2b((v.x - mean) * rstd * gg.x + bb.x);
    o4.y = f2b((v.y - mean) * rstd * gg.y + bb.y);
    o4.z = f2b((v.z - mean) * rstd * gg.z + bb.z);
    o4.w = f2b((v.w - mean) * rstd * gg.w + bb.w);
    ((ushort4*)(out + (size_t)bt * D_))[i] = o4;
}

// ---------------- fp32 -> bf16 convert (no transpose) ----------------
__global__ __launch_bounds__(256) void conv_kernel(
        const float* __restrict__ s, bf16_t* __restrict__ d, int n4) {
    int i = blockIdx.x * 256 + threadIdx.x;
    if (i >= n4) return;
    float4 f = ((const float4*)s)[i];
    ushort4 u = make_ushort4(f2b(f.x), f2b(f.y), f2b(f.z), f2b(f.w));
    ((ushort4*)d)[i] = u;
}

// ------------- fp32 [K][N] -> bf16 [N][K] transpose-convert, z = layer -----
__global__ __launch_bounds__(256) void tconv_kernel(
        const float* __restrict__ src, bf16_t* __restrict__ dst, int K, int N) {
    size_t ls = (size_t)K * N;
    const float* s = src + blockIdx.z * ls;
    bf16_t* d = dst + blockIdx.z * ls;
    __shared__ float tile[32][33];
    int n0 = blockIdx.x * 32, k0 = blockIdx.y * 32;
    int c = threadIdx.x & 31, r8 = threadIdx.x >> 5;
    #pragma unroll
    for (int i = 0; i < 4; ++i) {
        int r = r8 + i * 8;
        tile[r][c] = s[(size_t)(k0 + r) * N + n0 + c];
    }
    __syncthreads();
    #pragma unroll
    for (int i = 0; i < 4; ++i) {
        int r = r8 + i * 8;
        d[(size_t)(n0 + r) * K + k0 + c] = __float2bfloat16(tile[c][r]);
    }
}

// ---------------- bf16 MFMA GEMM (BK=64, swizzled LDS, XCD swizzle) --------
// C[M,N] = epi(A[M,K](bf16) @ Bt[N,K]^T + bias) (+res) ; 128x128 tile, BK=64.
// LDS swizzle (rule #21): linear gl16 dest + inverse-swizzled global source
// (slot ^= row&7) + same XOR on read -> ds_read_b128 spreads over 8 slots.
template<int ACT, bool OBF, bool RES, bool CONVB>
__global__ __launch_bounds__(256) void mm_kernel(
        const bf16_t* __restrict__ A,
        const bf16_t* __restrict__ Bt,   // [N][K] bf16 (unless CONVB)
        const float*  __restrict__ Bf,   // [N][K] fp32 (if CONVB)
        const float*  __restrict__ bias,
        const float*  __restrict__ res,
        void* __restrict__ Cout,
        int M, int N, int K)
{
    __shared__ __align__(16) unsigned short As[128 * 64];
    __shared__ __align__(16) unsigned short Bs[128 * 64];
    // bijective XCD swizzle (m204) + column-major tile order (M fast)
    const int nwg = gridDim.x;
    const int orig = blockIdx.x;
    const int q8 = nwg >> 3, r8 = nwg & 7;
    const int xcd = orig & 7, lin = orig >> 3;
    const int wg = (xcd < r8) ? xcd * (q8 + 1) + lin
                              : r8 * (q8 + 1) + (xcd - r8) * q8 + lin;
    const int gym = M >> 7;
    const int by = wg % gym;
    const int bx = wg / gym;

    const int t    = threadIdx.x;
    const int row0 = by * 128;
    const int col0 = bx * 128;
    const int lane = t & 63;
    const int wid  = t >> 6;
    const int wm   = (wid & 1) * 64;
    const int wn   = (wid >> 1) * 64;
    const int fr   = lane & 15;
    const int fq   = lane >> 4;

    f32x4 acc[4][4];
    #pragma unroll
    for (int m = 0; m < 4; ++m)
        #pragma unroll
        for (int n = 0; n < 4; ++n)
            acc[m][n] = (f32x4)(0.0f);

    const unsigned short* Ab  = (const unsigned short*)A;
    const unsigned short* Btb = (const unsigned short*)Bt;

    for (int k0 = 0; k0 < K; k0 += 64) {
        __syncthreads();
        #pragma unroll
        for (int i = 0; i < 4; ++i) {
            int c = t + i * 256;
            int row = c >> 3;
            int sl  = (c & 7) ^ (row & 7);
            gl16(Ab + (size_t)(row0 + row) * K + k0 + sl * 8, As + (size_t)c * 8);
        }
        if (!CONVB) {
            #pragma unroll
            for (int i = 0; i < 4; ++i) {
                int c = t + i * 256;
                int row = c >> 3;
                int sl  = (c & 7) ^ (row & 7);
                gl16(Btb + (size_t)(col0 + row) * K + k0 + sl * 8, Bs + (size_t)c * 8);
            }
        } else {
            #pragma unroll
            for (int i = 0; i < 4; ++i) {
                int c = t + i * 256;
                int row = c >> 3;
                int sl  = (c & 7) ^ (row & 7);
                const float* sp = Bf + (size_t)(col0 + row) * K + k0 + sl * 8;
                float4 f0 = ((const float4*)sp)[0];
                float4 f1 = ((const float4*)sp)[1];
                short8 pk;
                pk[0] = f2b(f0.x); pk[1] = f2b(f0.y); pk[2] = f2b(f0.z); pk[3] = f2b(f0.w);
                pk[4] = f2b(f1.x); pk[5] = f2b(f1.y); pk[6] = f2b(f1.z); pk[7] = f2b(f1.w);
                *(short8*)(Bs + (size_t)c * 8) = pk;
            }
        }
        __syncthreads();

        #pragma unroll
        for (int kk = 0; kk < 2; ++kk) {
            short8 av[4], bv[4];
            #pragma unroll
            for (int m = 0; m < 4; ++m) {
                int R = wm + m * 16 + fr;
                int sl = (kk * 4 + fq) ^ (fr & 7);
                av[m] = *(const short8*)(As + (size_t)R * 64 + sl * 8);
            }
            #pragma unroll
            for (int n = 0; n < 4; ++n) {
                int R = wn + n * 16 + fr;
                int sl = (kk * 4 + fq) ^ (fr & 7);
                bv[n] = *(const short8*)(Bs + (size_t)R * 64 + sl * 8);
            }
            #pragma unroll
            for (int m = 0; m < 4; ++m)
                #pragma unroll
                for (int n = 0; n < 4; ++n)
                    acc[m][n] = __builtin_amdgcn_mfma_f32_16x16x32_bf16(av[m], bv[n], acc[m][n], 0, 0, 0);
        }
    }

    // epilogue: C row = row0+wm+m*16+fq*4+r, col = col0+wn+n*16+fr
    #pragma unroll
    for (int n = 0; n < 4; ++n) {
        int col = col0 + wn + n * 16 + fr;
        float bb = bias ? bias[col] : 0.0f;
        #pragma unroll
        for (int m = 0; m < 4; ++m) {
            int rbase = row0 + wm + m * 16 + fq * 4;
            #pragma unroll
            for (int r = 0; r < 4; ++r) {
                float v = acc[m][n][r] + bb;
                if (ACT == 1) v = gelu_exact(v);
                size_t off = (size_t)(rbase + r) * N + col;
                if (RES) v += res[off];
                if (OBF) ((bf16_t*)Cout)[off] = __float2bfloat16(v);
                else     ((float*)Cout)[off]  = v;
            }
        }
    }
}

// ---------------- MFMA flash attention, 128-row Q tile, 8 waves ------------
// qkv bf16 [BT][3D]; y bf16 [BT][D]. Wave w owns q rows qt*128+w*16..+16.
// Fragment maps as validated: A row=lane&15, k=(lane>>4)*8; Bt col=lane&15;
// C row=(lane>>4)*4+r, col=lane&15.
__global__ __launch_bounds__(512, 2) void flash_kernel(
        const bf16_t* __restrict__ qkv, bf16_t* __restrict__ y)
{
    __shared__ __align__(16) unsigned short Ks[64][72];    // [j][d]
    __shared__ __align__(16) unsigned short Vt[64][72];    // [d][j]
    __shared__ __align__(16) unsigned short Pls[128][72];  // [q][j] wave-private rows

    const int qt = (T_ / 128 - 1) - (blockIdx.x >> 6);  // big tiles first
    const int bh = blockIdx.x & 63;
    const int h  = bh & (H_ - 1);
    const int b  = bh >> 3;
    const int t  = threadIdx.x;
    const int lane = t & 63;
    const int w    = t >> 6;
    const int fr   = lane & 15;
    const int fq   = lane >> 4;

    const unsigned short* qkvb = (const unsigned short*)qkv;

    // Q fragments in registers, rows = qt*128 + w*16 + fr
    short8 avq[2];
    {
        const unsigned short* qrow = qkvb +
            (size_t)(b * T_ + qt * 128 + w * 16 + fr) * (3 * D_) + h * DH_;
        avq[0] = *(const short8*)(qrow + fq * 8);
        avq[1] = *(const short8*)(qrow + 32 + fq * 8);
    }

    float mi[4], li[4];
    f32x4 oacc[4];
    #pragma unroll
    for (int r = 0; r < 4; ++r) { mi[r] = -INFINITY; li[r] = 0.0f; }
    #pragma unroll
    for (int d = 0; d < 4; ++d) oacc[d] = (f32x4)(0.0f);

    const int nt = 2 * qt + 2;
    for (int jt = 0; jt < nt; ++jt) {
        __syncthreads();
        {   // stage K [j][d] and V transposed [d][j]; 512 thr x 1 chunk each
            int j = t >> 3, seg = t & 7;
            const unsigned short* kr = qkvb +
                (size_t)(b * T_ + jt * 64 + j) * (3 * D_) + D_ + h * DH_ + seg * 8;
            *(short8*)&Ks[j][seg * 8] = *(const short8*)kr;
            short8 vv = *(const short8*)(kr + D_);
            int dbase = seg * 8;
            Vt[dbase + 0][j] = vv[0]; Vt[dbase + 1][j] = vv[1];
            Vt[dbase + 2][j] = vv[2]; Vt[dbase + 3][j] = vv[3];
            Vt[dbase + 4][j] = vv[4]; Vt[dbase + 5][j] = vv[5];
            Vt[dbase + 6][j] = vv[6]; Vt[dbase + 7][j] = vv[7];
        }
        __syncthreads();

        // S = Q @ K^T : 16 q-rows x 64 j per wave
        f32x4 s[4];
        #pragma unroll
        for (int jb = 0; jb < 4; ++jb) s[jb] = (f32x4)(0.0f);
        #pragma unroll
        for (int ks = 0; ks < 2; ++ks) {
            #pragma unroll
            for (int jb = 0; jb < 4; ++jb) {
                short8 bv = *(const short8*)(&Ks[jb * 16 + fr][ks * 32 + fq * 8]);
                s[jb] = __builtin_amdgcn_mfma_f32_16x16x32_bf16(avq[ks], bv, s[jb], 0, 0, 0);
            }
        }

        // scale + causal mask: jg = jt*64+jb*16+fr vs qg = qt*128+w*16+fq*4+r
        float sv[4][4];
        const int qgb = qt * 128 + w * 16 + fq * 4;
        #pragma unroll
        for (int jb = 0; jb < 4; ++jb) {
            int jg = jt * 64 + jb * 16 + fr;
            #pragma unroll
            for (int r = 0; r < 4; ++r) {
                float x = s[jb][r] * 0.125f;
                sv[jb][r] = (jg > qgb + r) ? -INFINITY : x;
            }
        }

        // online softmax per C-row r: reduce across jb then fr lanes
        #pragma unroll
        for (int r = 0; r < 4; ++r) {
            float tm = fmaxf(fmaxf(sv[0][r], sv[1][r]), fmaxf(sv[2][r], sv[3][r]));
            tm = fmaxf(tm, __shfl_xor(tm, 1));
            tm = fmaxf(tm, __shfl_xor(tm, 2));
            tm = fmaxf(tm, __shfl_xor(tm, 4));
            tm = fmaxf(tm, __shfl_xor(tm, 8));
            float mnew = fmaxf(mi[r], tm);
            float corr = __expf(mi[r] - mnew);
            float tsum = 0.0f;
            #pragma unroll
            for (int jb = 0; jb < 4; ++jb) {
                float p = __expf(sv[jb][r] - mnew);
                sv[jb][r] = p;
                tsum += p;
            }
            tsum += __shfl_xor(tsum, 1);
            tsum += __shfl_xor(tsum, 2);
            tsum += __shfl_xor(tsum, 4);
            tsum += __shfl_xor(tsum, 8);
            li[r] = li[r] * corr + tsum;
            mi[r] = mnew;
            #pragma unroll
            for (int db = 0; db < 4; ++db) oacc[db][r] *= corr;
        }

        // P -> LDS (wave-private rows; no barrier needed), then PV
        #pragma unroll
        for (int jb = 0; jb < 4; ++jb)
            #pragma unroll
            for (int r = 0; r < 4; ++r)
                Pls[w * 16 + fq * 4 + r][jb * 16 + fr] = f2b(sv[jb][r]);

        #pragma unroll
        for (int ks = 0; ks < 2; ++ks) {
            short8 ap = *(const short8*)(&Pls[w * 16 + fr][ks * 32 + fq * 8]);
            #pragma unroll
            for (int db = 0; db < 4; ++db) {
                short8 bv = *(const short8*)(&Vt[db * 16 + fr][ks * 32 + fq * 8]);
                oacc[db] = __builtin_amdgcn_mfma_f32_16x16x32_bf16(ap, bv, oacc[db], 0, 0, 0);
            }
        }
    }

    // write y: row = qt*128 + w*16 + fq*4 + r, col = h*64 + db*16 + fr
    unsigned short* yb = (unsigned short*)y;
    #pragma unroll
    for (int r = 0; r < 4; ++r) {
        float inv = 1.0f / li[r];
        size_t row = (size_t)(b * T_ + qt * 128 + w * 16 + fq * 4 + r);
        #pragma unroll
        for (int db = 0; db < 4; ++db)
            yb[row * D_ + h * DH_ + db * 16 + fr] = f2b(oacc[db][r] * inv);
    }
}

// ---------------- launcher ----------------
extern "C" void kernel_launch(void* const* d_in, const int* in_sizes, int n_in,
                              void* d_out, int out_size, void* d_ws, size_t ws_size,
                              hipStream_t stream) {
    const int*   idx   = (const int*)  d_in[0];
    const float* wte   = (const float*)d_in[1];
    const float* wpe   = (const float*)d_in[2];
    const float* ln1_g = (const float*)d_in[3];
    const float* ln1_b = (const float*)d_in[4];
    const float* w_qkv = (const float*)d_in[5];
    const float* b_qkv = (const float*)d_in[6];
    const float* w_ao  = (const float*)d_in[7];
    const float* b_ao  = (const float*)d_in[8];
    const float* ln2_g = (const float*)d_in[9];
    const float* ln2_b = (const float*)d_in[10];
    const float* w_fc  = (const float*)d_in[11];
    const float* b_fc  = (const float*)d_in[12];
    const float* w_pr  = (const float*)d_in[13];
    const float* b_pr  = (const float*)d_in[14];
    const float* lnf_g = (const float*)d_in[15];
    const float* lnf_b = (const float*)d_in[16];
    float* outf = (float*)d_out;

    // scratch carved from d_out (dead before the head GEMM overwrites it)
    char* base = (char*)d_out;
    size_t off = 0;
    auto alloc = [&](size_t bytes) {
        void* p = base + off;
        off += (bytes + 255) & ~(size_t)255;
        return p;
    };
    bf16_t* wqkvT = (bf16_t*)alloc((size_t)L_ * 3 * D_ * D_ * 2);
    bf16_t* waoT  = (bf16_t*)alloc((size_t)L_ * D_ * D_ * 2);
    bf16_t* wfcT  = (bf16_t*)alloc((size_t)L_ * DFF_ * D_ * 2);
    bf16_t* wprT  = (bf16_t*)alloc((size_t)L_ * D_ * DFF_ * 2);
    bf16_t* qkvb  = (bf16_t*)alloc((size_t)BT_ * 3 * D_ * 2);
    bf16_t* yb    = (bf16_t*)alloc((size_t)BT_ * D_ * 2);
    bf16_t* hab   = (bf16_t*)alloc((size_t)BT_ * D_ * 2);
    bf16_t* fcb   = (bf16_t*)alloc((size_t)BT_ * DFF_ * 2);
    float*  xb    = (float*) alloc((size_t)BT_ * D_ * 4);

    // ws: final-LN output must survive the head GEMM (which clobbers d_out)
    bf16_t* hfin = (bf16_t*)d_ws;
    size_t hbytes = ((size_t)BT_ * D_ * 2 + 255) & ~(size_t)255;
    bool wte_ws = ws_size >= hbytes + (size_t)V_ * D_ * 2 + 256;
    bf16_t* wteb = wte_ws ? (bf16_t*)((char*)d_ws + hbytes) : nullptr;

    if (wte_ws)
        conv_kernel<<<(V_ * D_ / 4 + 255) / 256, 256, 0, stream>>>(wte, wteb, V_ * D_ / 4);
    tconv_kernel<<<dim3(3 * D_ / 32, D_ / 32, L_), 256, 0, stream>>>(w_qkv, wqkvT, D_, 3 * D_);
    tconv_kernel<<<dim3(D_ / 32, D_ / 32, L_), 256, 0, stream>>>(w_ao, waoT, D_, D_);
    tconv_kernel<<<dim3(DFF_ / 32, D_ / 32, L_), 256, 0, stream>>>(w_fc, wfcT, D_, DFF_);
    tconv_kernel<<<dim3(D_ / 32, DFF_ / 32, L_), 256, 0, stream>>>(w_pr, wprT, DFF_, D_);

    embed_kernel<<<BT_, 128, 0, stream>>>(idx, wte, wpe, xb);

    for (int l = 0; l < L_; ++l) {
        ln_kernel<<<BT_, 128, 0, stream>>>(xb, ln1_g + l * D_, ln1_b + l * D_, hab);
        mm_kernel<0, true, false, false><<<12 * 64, 256, 0, stream>>>(
            hab, wqkvT + (size_t)l * 3 * D_ * D_, nullptr, b_qkv + (size_t)l * 3 * D_,
            nullptr, qkvb, BT_, 3 * D_, D_);
        flash_kernel<<<512, 512, 0, stream>>>(qkvb, yb);
        mm_kernel<0, false, true, false><<<4 * 64, 256, 0, stream>>>(
            yb, waoT + (size_t)l * D_ * D_, nullptr, b_ao + (size_t)l * D_,
            xb, xb, BT_, D_, D_);
        ln_kernel<<<BT_, 128, 0, stream>>>(xb, ln2_g + l * D_, ln2_b + l * D_, hab);
        mm_kernel<1, true, false, false><<<16 * 64, 256, 0, stream>>>(
            hab, wfcT + (size_t)l * DFF_ * D_, nullptr, b_fc + (size_t)l * DFF_,
            nullptr, fcb, BT_, DFF_, D_);
        mm_kernel<0, false, true, false><<<4 * 64, 256, 0, stream>>>(
            fcb, wprT + (size_t)l * D_ * DFF_, nullptr, b_pr + (size_t)l * D_,
            xb, xb, BT_, D_, DFF_);
    }

    ln_kernel<<<BT_, 128, 0, stream>>>(xb, lnf_g, lnf_b, hfin);
    if (wte_ws)
        mm_kernel<0, false, false, false><<<250 * 64, 256, 0, stream>>>(
            hfin, wteb, nullptr, nullptr, nullptr, outf, BT_, V_, D_);
    else
        mm_kernel<0, false, false, true><<<250 * 64, 256, 0, stream>>>(
            hfin, nullptr, wte, nullptr, nullptr, outf, BT_, V_, D_);
}